// Round 1
// baseline (1260.489 us; speedup 1.0000x reference)
//
#include <hip/hip_runtime.h>
#include <cstdint>

// ---------------------------------------------------------------------------
// MXFP4 GPT-OSS MoE experts: dense all-expert GLU MLP.
//   E=8 experts, H=I=2880, T=1024 tokens.
//   GEMM1: gate_up[e,t,f] = sum_h x[t,h] * W1[e,f,h]   (W1 rows=f, K=h contig)
//   act   = glu(gate,up) fused in epilogue, written bf16 to ws
//   GEMM2: out[t,h] += rw[t,e] * (sum_i act[e,t,i]*W2[e,h,i] + bias)
// Weights are MXFP4: blocks [E,R,G,16] int32 (one BYTE per int32, 2 nibbles =
// 2 weights), scales [E,R,G] biased exponents. Dequant fused into GEMM staging.
// ---------------------------------------------------------------------------

typedef float  floatx4 __attribute__((ext_vector_type(4)));
typedef __bf16 bf16x8  __attribute__((ext_vector_type(8)));

#define E8   8
#define Hdim 2880
#define Idim 2880
#define Ttok 1024
#define R1   5760   // 2*I rows of gate_up weights
#define Gg   90     // groups per row (K/32)

// global -> LDS direct copy, 16B per lane. LDS dest = wave-uniform base + lane*16.
__device__ __forceinline__ void load_lds16(const void* gptr, void* lptr) {
  __builtin_amdgcn_global_load_lds(
      (const __attribute__((address_space(1))) uint32_t*)gptr,
      (__attribute__((address_space(3))) uint32_t*)lptr, 16, 0, 0);
}

__device__ __forceinline__ uint32_t f2bf(float f) {  // RTN-even fp32->bf16
  uint32_t u = __float_as_uint(f);
  return (u + 0x7FFFu + ((u >> 16) & 1u)) >> 16;
}

// One packed byte -> two bf16 (lo nibble = even element in low half).
// |fp4|*2 LUT packed in one constant: idx 0..7 -> 0,1,2,3,4,6,8,12.
// hs = 2^(s-128) (scale * 0.5). fp4*2^k is exact in bf16 -> truncate.
__device__ __forceinline__ uint32_t dq_byte(uint32_t b, float hs) {
  const uint32_t LUT = 0xC8643210u;
  uint32_t lo = b & 15u, hi = (b >> 4) & 15u;
  float vl = (float)((LUT >> ((lo & 7u) << 2)) & 15u) * hs;
  float vh = (float)((LUT >> ((hi & 7u) << 2)) & 15u) * hs;
  uint32_t ul = __float_as_uint(vl) ^ ((lo & 8u) << 28);
  uint32_t uh = __float_as_uint(vh) ^ ((hi & 8u) << 28);
  return (ul >> 16) | (uh & 0xFFFF0000u);
}

// ---------------------------------------------------------------------------
__global__ void cvt_x_kernel(const float* __restrict__ x, uint16_t* __restrict__ xb, int n) {
  int i = (blockIdx.x * 256 + threadIdx.x) * 4;
  if (i >= n) return;
  float4 v = *(const float4*)(x + i);
  ushort4 o = make_ushort4((uint16_t)f2bf(v.x), (uint16_t)f2bf(v.y),
                           (uint16_t)f2bf(v.z), (uint16_t)f2bf(v.w));
  *(ushort4*)(xb + i) = o;
}

// ---------------------------------------------------------------------------
// GEMM1: BM=128 tokens x BN=128 f-rows (= 64 i values, gate/up deinterleaved
// into LDS rows [g0..31][u0..31][g32..63][u32..63]), BK=64. 256 thr = 4 waves
// (2x2), wave tile 64m x 64n. LDS chunk-XOR swizzle: chunk c of row r stored
// at c^(r&7)  (chunk = 16B = one MFMA frag k-span).
__global__ __launch_bounds__(256) void gemm1_kernel(
    const uint16_t* __restrict__ xb, const int* __restrict__ blocks,
    const int* __restrict__ scales, const float* __restrict__ bias,
    uint16_t* __restrict__ act) {
  __shared__ uint16_t sA[128 * 64];
  __shared__ uint16_t sB[128 * 64];
  const int tid  = threadIdx.x;
  const int lane = tid & 63, wv = tid >> 6;
  const int wx = wv & 1, wy = wv >> 1;
  const int col = lane & 15, quad = lane >> 4;
  const int e  = blockIdx.z;
  const int i0 = blockIdx.x * 64;
  const int t0 = blockIdx.y * 128;

  floatx4 acc[4][4] = {};

  // B staging: 2 threads per f-row, 32 k-values (= 1 scale group) each.
  const int d  = tid >> 1, kh = tid & 1;             // d: f-offset in tile
  const int rho = ((d >> 6) << 6) | ((d & 1) << 5) | ((d >> 1) & 31);  // deinterleave
  const size_t brow = ((size_t)e * R1 + (2 * i0 + d)) * Gg;

  for (int kt = 0; kt < 45; ++kt) {
    __syncthreads();
    {  // stage A (async DMA, swizzled via global address permutation)
      const int k0 = kt * 64;
      #pragma unroll
      for (int q = 0; q < 4; ++q) {
        int L = wv * 256 + q * 64 + lane;   // chunk index in tile
        int row = L >> 3;
        int c = (L & 7) ^ (row & 7);        // source chunk for this slot
        load_lds16(xb + (size_t)(t0 + row) * Hdim + k0 + c * 8,
                   &sA[(size_t)(wv * 256 + q * 64) * 8]);
      }
    }
    {  // stage B: load packed bytes, dequant, swizzled ds_write_b128
      const int g = kt * 2 + kh;
      const int4* bp = (const int4*)(blocks + (brow + g) * 16);
      int4 w0 = bp[0], w1 = bp[1], w2 = bp[2], w3 = bp[3];
      int s = scales[brow + g];
      float hs = __uint_as_float((uint32_t)(s - 1) << 23);
      const int base = rho * 64, m = rho & 7;
      uint4 o;
      o.x = dq_byte((uint32_t)w0.x, hs); o.y = dq_byte((uint32_t)w0.y, hs);
      o.z = dq_byte((uint32_t)w0.z, hs); o.w = dq_byte((uint32_t)w0.w, hs);
      *(uint4*)&sB[base + (((kh << 2) | 0) ^ m) * 8] = o;
      o.x = dq_byte((uint32_t)w1.x, hs); o.y = dq_byte((uint32_t)w1.y, hs);
      o.z = dq_byte((uint32_t)w1.z, hs); o.w = dq_byte((uint32_t)w1.w, hs);
      *(uint4*)&sB[base + (((kh << 2) | 1) ^ m) * 8] = o;
      o.x = dq_byte((uint32_t)w2.x, hs); o.y = dq_byte((uint32_t)w2.y, hs);
      o.z = dq_byte((uint32_t)w2.z, hs); o.w = dq_byte((uint32_t)w2.w, hs);
      *(uint4*)&sB[base + (((kh << 2) | 2) ^ m) * 8] = o;
      o.x = dq_byte((uint32_t)w3.x, hs); o.y = dq_byte((uint32_t)w3.y, hs);
      o.z = dq_byte((uint32_t)w3.z, hs); o.w = dq_byte((uint32_t)w3.w, hs);
      *(uint4*)&sB[base + (((kh << 2) | 3) ^ m) * 8] = o;
    }
    __syncthreads();
    #pragma unroll
    for (int ks = 0; ks < 2; ++ks) {
      bf16x8 af[4], bfr[4];
      #pragma unroll
      for (int fm = 0; fm < 4; ++fm) {
        int row = wy * 64 + fm * 16 + col;
        int c = ((ks << 2) | quad) ^ (row & 7);
        af[fm] = *(const bf16x8*)&sA[row * 64 + c * 8];
      }
      #pragma unroll
      for (int fn = 0; fn < 4; ++fn) {
        int row = wx * 64 + fn * 16 + col;
        int c = ((ks << 2) | quad) ^ (row & 7);
        bfr[fn] = *(const bf16x8*)&sB[row * 64 + c * 8];
      }
      #pragma unroll
      for (int fm = 0; fm < 4; ++fm)
        #pragma unroll
        for (int fn = 0; fn < 4; ++fn)
          acc[fm][fn] = __builtin_amdgcn_mfma_f32_16x16x32_bf16(
              af[fm], bfr[fn], acc[fm][fn], 0, 0, 0);
    }
  }

  // epilogue: pair gate frag fn with up frag fn+2, apply bias + GLU, store bf16
  #pragma unroll
  for (int fm = 0; fm < 4; ++fm) {
    #pragma unroll
    for (int p = 0; p < 2; ++p) {
      floatx4 ga = acc[fm][p], ua = acc[fm][p + 2];
      int ig = i0 + wx * 32 + p * 16 + col;
      float bg = bias[(size_t)e * R1 + 2 * ig];
      float bu = bias[(size_t)e * R1 + 2 * ig + 1];
      #pragma unroll
      for (int r = 0; r < 4; ++r) {
        int t = t0 + wy * 64 + fm * 16 + quad * 4 + r;
        float gate = fminf(ga[r] + bg, 7.0f);
        float up   = fminf(fmaxf(ua[r] + bu, -7.0f), 7.0f);
        float glu  = gate / (1.0f + __expf(-1.702f * gate));
        float a    = (up + 1.0f) * glu;
        act[((size_t)e * Ttok + t) * Idim + ig] = (uint16_t)f2bf(a);
      }
    }
  }
}

// ---------------------------------------------------------------------------
// GEMM2: BM=128 tokens x BN=64 h-rows, BK=64. Wave tile 64m x 32n.
// Epilogue: atomicAdd of rw[t,e]*(acc+bias) into zeroed out.
__global__ __launch_bounds__(256) void gemm2_kernel(
    const uint16_t* __restrict__ act, const int* __restrict__ blocks,
    const int* __restrict__ scales, const float* __restrict__ bias,
    const float* __restrict__ rw, float* __restrict__ out) {
  __shared__ uint16_t sA[128 * 64];
  __shared__ uint16_t sB[64 * 64];
  const int tid  = threadIdx.x;
  const int lane = tid & 63, wv = tid >> 6;
  const int wx = wv & 1, wy = wv >> 1;
  const int col = lane & 15, quad = lane >> 4;
  const int e  = blockIdx.z;
  const int h0 = blockIdx.x * 64;
  const int t0 = blockIdx.y * 128;

  floatx4 acc[4][2] = {};

  // B staging: 4 threads per h-row, 16 k-values (8 int32 = 2 chunks) each.
  const int d = tid >> 2, sub = tid & 3;
  const size_t brow = ((size_t)e * Hdim + (h0 + d)) * Gg;
  const uint16_t* aB = act + (size_t)e * Ttok * Idim;

  for (int kt = 0; kt < 45; ++kt) {
    __syncthreads();
    {
      const int k0 = kt * 64;
      #pragma unroll
      for (int q = 0; q < 4; ++q) {
        int L = wv * 256 + q * 64 + lane;
        int row = L >> 3;
        int c = (L & 7) ^ (row & 7);
        load_lds16(aB + (size_t)(t0 + row) * Idim + k0 + c * 8,
                   &sA[(size_t)(wv * 256 + q * 64) * 8]);
      }
    }
    {
      const int g = kt * 2 + (sub >> 1);
      const int4* bp = (const int4*)(blocks + (brow + g) * 16 + (sub & 1) * 8);
      int4 w0 = bp[0], w1 = bp[1];
      int s = scales[brow + g];
      float hs = __uint_as_float((uint32_t)(s - 1) << 23);
      const int m = d & 7;
      uint4 o;
      o.x = dq_byte((uint32_t)w0.x, hs); o.y = dq_byte((uint32_t)w0.y, hs);
      o.z = dq_byte((uint32_t)w0.z, hs); o.w = dq_byte((uint32_t)w0.w, hs);
      *(uint4*)&sB[d * 64 + ((2 * sub) ^ m) * 8] = o;
      o.x = dq_byte((uint32_t)w1.x, hs); o.y = dq_byte((uint32_t)w1.y, hs);
      o.z = dq_byte((uint32_t)w1.z, hs); o.w = dq_byte((uint32_t)w1.w, hs);
      *(uint4*)&sB[d * 64 + ((2 * sub + 1) ^ m) * 8] = o;
    }
    __syncthreads();
    #pragma unroll
    for (int ks = 0; ks < 2; ++ks) {
      bf16x8 af[4], bfr[2];
      #pragma unroll
      for (int fm = 0; fm < 4; ++fm) {
        int row = wy * 64 + fm * 16 + col;
        int c = ((ks << 2) | quad) ^ (row & 7);
        af[fm] = *(const bf16x8*)&sA[row * 64 + c * 8];
      }
      #pragma unroll
      for (int fn = 0; fn < 2; ++fn) {
        int row = wx * 32 + fn * 16 + col;
        int c = ((ks << 2) | quad) ^ (row & 7);
        bfr[fn] = *(const bf16x8*)&sB[row * 64 + c * 8];
      }
      #pragma unroll
      for (int fm = 0; fm < 4; ++fm)
        #pragma unroll
        for (int fn = 0; fn < 2; ++fn)
          acc[fm][fn] = __builtin_amdgcn_mfma_f32_16x16x32_bf16(
              af[fm], bfr[fn], acc[fm][fn], 0, 0, 0);
    }
  }

  #pragma unroll
  for (int fm = 0; fm < 4; ++fm) {
    #pragma unroll
    for (int fn = 0; fn < 2; ++fn) {
      int h = h0 + wx * 32 + fn * 16 + col;
      float db = bias[(size_t)e * Hdim + h];
      #pragma unroll
      for (int r = 0; r < 4; ++r) {
        int t = t0 + wy * 64 + fm * 16 + quad * 4 + r;
        float wgt = rw[t * E8 + e];
        atomicAdd(out + (size_t)t * Hdim + h, wgt * (acc[fm][fn][r] + db));
      }
    }
  }
}

// ---------------------------------------------------------------------------
extern "C" void kernel_launch(void* const* d_in, const int* in_sizes, int n_in,
                              void* d_out, int out_size, void* d_ws, size_t ws_size,
                              hipStream_t stream) {
  (void)in_sizes; (void)n_in; (void)ws_size;
  const float* x        = (const float*)d_in[0];
  const float* rw       = (const float*)d_in[1];
  const int*   gub_b    = (const int*)d_in[2];
  const int*   gub_s    = (const int*)d_in[3];
  const float* gub_bias = (const float*)d_in[4];
  const int*   dwn_b    = (const int*)d_in[5];
  const int*   dwn_s    = (const int*)d_in[6];
  const float* dwn_bias = (const float*)d_in[7];
  float* out = (float*)d_out;

  // ws layout: x_bf16 [T,H] (5.9 MB) | act_bf16 [E,T,I] (47.2 MB)
  uint16_t* xb  = (uint16_t*)d_ws;
  uint16_t* act = xb + (size_t)Ttok * Hdim;

  hipMemsetAsync(out, 0, (size_t)out_size * sizeof(float), stream);
  cvt_x_kernel<<<dim3((Ttok * Hdim / 4 + 255) / 256), 256, 0, stream>>>(x, xb, Ttok * Hdim);
  gemm1_kernel<<<dim3(45, 8, 8), 256, 0, stream>>>(xb, gub_b, gub_s, gub_bias, act);
  gemm2_kernel<<<dim3(45, 8, 8), 256, 0, stream>>>(act, dwn_b, dwn_s, dwn_bias, rw, out);
}

// Round 2
// 1257.626 us; speedup vs baseline: 1.0023x; 1.0023x over previous
//
#include <hip/hip_runtime.h>
#include <cstdint>

// ---------------------------------------------------------------------------
// MXFP4 GPT-OSS MoE experts: dense all-expert GLU MLP.
//   GEMM1: gate_up[e,t,f] = sum_h x[t,h] * W1[e,f,h]; GLU fused in epilogue,
//          act written bf16 to ws.
//   GEMM2: out[t,h] = sum_e rw[t,e] * (sum_i act[e,t,i]*W2[e,h,i] + bias[e,h])
//          expert-innermost per block -> fp32 register accumulation, NO atomics.
// Weights MXFP4: blocks [E,R,G,16] int32 (ONE byte per int32 = 2 nibbles),
// scales [E,R,G] biased exponents. Dequant = v_perm byte-LUT, exact bf16 bits.
// ---------------------------------------------------------------------------

typedef float  floatx4 __attribute__((ext_vector_type(4)));
typedef __bf16 bf16x8  __attribute__((ext_vector_type(8)));

#define E8   8
#define Hdim 2880
#define Idim 2880
#define Ttok 1024
#define R1   5760   // 2*I rows of gate_up weights
#define Gg   90     // groups per row (K/32)

__device__ __forceinline__ void load_lds16(const void* gptr, void* lptr) {
  __builtin_amdgcn_global_load_lds(
      (const __attribute__((address_space(1))) uint32_t*)gptr,
      (__attribute__((address_space(3))) uint32_t*)lptr, 16, 0, 0);
}

__device__ __forceinline__ uint32_t f2bf(float f) {  // RTN-even fp32->bf16
  uint32_t u = __float_as_uint(f);
  return (u + 0x7FFFu + ((u >> 16) & 1u)) >> 16;
}

// perm(hi, lo, sel): dst byte k = concat(hi:bytes4-7, lo:bytes0-3)[sel_k]
__device__ __forceinline__ uint32_t perm(uint32_t hi, uint32_t lo, uint32_t sel) {
  return __builtin_amdgcn_perm(hi, lo, sel);
}

// Per-scale-group LUT: bf16 bit patterns of FP4 magnitudes 0..7 scaled by
// 2^(s-127), split into low/high bytes for v_perm lookup. Entry 0 stays 0.
struct DqLut { uint32_t Ll, Lh, Hl, Hh; };  // L/H bytes, entries 0-3 (l), 4-7 (h)

__device__ __forceinline__ DqLut make_lut(int s) {
  uint32_t A  = ((uint32_t)(s - 127) << 7) & 0xFFFFu;  // exponent-field delta
  uint32_t e1 = (0x3F00u + A) & 0xFFFFu;   // 0.5 * 2^sc
  uint32_t e2 = (0x3F80u + A) & 0xFFFFu;   // 1.0
  uint32_t e3 = (0x3FC0u + A) & 0xFFFFu;   // 1.5
  uint32_t e4 = (0x4000u + A) & 0xFFFFu;   // 2.0
  uint32_t e5 = (0x4040u + A) & 0xFFFFu;   // 3.0
  uint32_t e6 = (0x4080u + A) & 0xFFFFu;   // 4.0
  uint32_t e7 = (0x40C0u + A) & 0xFFFFu;   // 6.0
  uint32_t B01 = e1 << 16;                 // entry0 = 0x0000
  uint32_t B23 = e2 | (e3 << 16);
  uint32_t B45 = e4 | (e5 << 16);
  uint32_t B67 = e6 | (e7 << 16);
  DqLut L;
  L.Ll = perm(B23, B01, 0x06040200u);      // low bytes of entries 0..3
  L.Hl = perm(B23, B01, 0x07050301u);      // high bytes of entries 0..3
  L.Lh = perm(B67, B45, 0x06040200u);      // low bytes of entries 4..7
  L.Hh = perm(B67, B45, 0x07050301u);      // high bytes of entries 4..7
  return L;
}

// 4 source dwords (1 packed byte each, 2 nibbles) -> 8 bf16 (4 dwords).
// Element order: byte b -> elements 2b (lo nibble), 2b+1 (hi nibble).
__device__ __forceinline__ uint4 dq8(const DqLut& L, int4 wr) {
  uint32_t p = perm((uint32_t)wr.y, (uint32_t)wr.x, 0x04000400u);
  uint32_t q = perm((uint32_t)wr.w, (uint32_t)wr.z, 0x04000400u);
  uint32_t w = perm(q, p, 0x05040100u);            // [x0,y0,z0,w0] bytes
  uint32_t ilo = w & 0x07070707u;                  // lo-nibble magnitude idx
  uint32_t ihi = (w >> 4) & 0x07070707u;           // hi-nibble magnitude idx
  uint32_t Llo = perm(L.Lh, L.Ll, ilo);
  uint32_t Hlo = perm(L.Hh, L.Hl, ilo) | ((w << 4) & 0x80808080u);  // + sign
  uint32_t Lhi = perm(L.Lh, L.Ll, ihi);
  uint32_t Hhi = perm(L.Hh, L.Hl, ihi) | (w & 0x80808080u);
  uint32_t t0 = perm(Hlo, Llo, 0x05010400u);       // [L0,H0,L1,H1] (lo nibbles)
  uint32_t t1 = perm(Hlo, Llo, 0x07030602u);       // [L2,H2,L3,H3]
  uint32_t t2 = perm(Hhi, Lhi, 0x05010400u);
  uint32_t t3 = perm(Hhi, Lhi, 0x07030602u);
  uint4 o;
  o.x = perm(t2, t0, 0x05040100u);  // bf16(lo0) | bf16(hi0)<<16
  o.y = perm(t2, t0, 0x07060302u);
  o.z = perm(t3, t1, 0x05040100u);
  o.w = perm(t3, t1, 0x07060302u);
  return o;
}

// ---------------------------------------------------------------------------
__global__ void cvt_x_kernel(const float* __restrict__ x, uint16_t* __restrict__ xb, int n) {
  int i = (blockIdx.x * 256 + threadIdx.x) * 4;
  if (i >= n) return;
  float4 v = *(const float4*)(x + i);
  ushort4 o = make_ushort4((uint16_t)f2bf(v.x), (uint16_t)f2bf(v.y),
                           (uint16_t)f2bf(v.z), (uint16_t)f2bf(v.w));
  *(ushort4*)(xb + i) = o;
}

// ---------------------------------------------------------------------------
// GEMM1: BM=128 tokens x BN=128 f-rows (gate/up deinterleaved in LDS), BK=64.
// 4 waves 2x2, wave tile 64x64. Chunk-XOR swizzled LDS.
// Grid: (t-tile fastest, i-block, e) so blocks sharing weights are adjacent.
__global__ __launch_bounds__(256) void gemm1_kernel(
    const uint16_t* __restrict__ xb, const int* __restrict__ blocks,
    const int* __restrict__ scales, const float* __restrict__ bias,
    uint16_t* __restrict__ act) {
  __shared__ uint16_t sA[128 * 64];
  __shared__ uint16_t sB[128 * 64];
  const int tid  = threadIdx.x;
  const int lane = tid & 63, wv = tid >> 6;
  const int wx = wv & 1, wy = wv >> 1;
  const int col = lane & 15, quad = lane >> 4;
  const int e  = blockIdx.z;
  const int t0 = blockIdx.x * 128;
  const int i0 = blockIdx.y * 64;

  floatx4 acc[4][4] = {};

  const int d  = tid >> 1, kh = tid & 1;  // 2 threads per f-row, 1 group each
  const int rho = ((d >> 6) << 6) | ((d & 1) << 5) | ((d >> 1) & 31);  // deinterleave
  const size_t brow = ((size_t)e * R1 + (2 * i0 + d)) * Gg;

  for (int kt = 0; kt < 45; ++kt) {
    __syncthreads();
    {  // stage A (async DMA, swizzle applied on global address)
      const int k0 = kt * 64;
      #pragma unroll
      for (int q = 0; q < 4; ++q) {
        int L = wv * 256 + q * 64 + lane;
        int row = L >> 3;
        int c = (L & 7) ^ (row & 7);
        load_lds16(xb + (size_t)(t0 + row) * Hdim + k0 + c * 8,
                   &sA[(size_t)(wv * 256 + q * 64) * 8]);
      }
    }
    {  // stage B: perm-LUT dequant, swizzled ds_write_b128
      const int g = kt * 2 + kh;
      const int4* bp = (const int4*)(blocks + (brow + g) * 16);
      int4 w0 = bp[0], w1 = bp[1], w2 = bp[2], w3 = bp[3];
      DqLut L = make_lut(scales[brow + g]);
      const int base = rho * 64, m = rho & 7;
      *(uint4*)&sB[base + ((((kh << 2) | 0) ^ m) * 8)] = dq8(L, w0);
      *(uint4*)&sB[base + ((((kh << 2) | 1) ^ m) * 8)] = dq8(L, w1);
      *(uint4*)&sB[base + ((((kh << 2) | 2) ^ m) * 8)] = dq8(L, w2);
      *(uint4*)&sB[base + ((((kh << 2) | 3) ^ m) * 8)] = dq8(L, w3);
    }
    __syncthreads();
    #pragma unroll
    for (int ks = 0; ks < 2; ++ks) {
      bf16x8 af[4], bfr[4];
      #pragma unroll
      for (int fm = 0; fm < 4; ++fm) {
        int row = wy * 64 + fm * 16 + col;
        int c = ((ks << 2) | quad) ^ (row & 7);
        af[fm] = *(const bf16x8*)&sA[row * 64 + c * 8];
      }
      #pragma unroll
      for (int fn = 0; fn < 4; ++fn) {
        int row = wx * 64 + fn * 16 + col;
        int c = ((ks << 2) | quad) ^ (row & 7);
        bfr[fn] = *(const bf16x8*)&sB[row * 64 + c * 8];
      }
      #pragma unroll
      for (int fm = 0; fm < 4; ++fm)
        #pragma unroll
        for (int fn = 0; fn < 4; ++fn)
          acc[fm][fn] = __builtin_amdgcn_mfma_f32_16x16x32_bf16(
              af[fm], bfr[fn], acc[fm][fn], 0, 0, 0);
    }
  }

  #pragma unroll
  for (int fm = 0; fm < 4; ++fm) {
    #pragma unroll
    for (int p = 0; p < 2; ++p) {
      floatx4 ga = acc[fm][p], ua = acc[fm][p + 2];
      int ig = i0 + wx * 32 + p * 16 + col;
      float bg = bias[(size_t)e * R1 + 2 * ig];
      float bu = bias[(size_t)e * R1 + 2 * ig + 1];
      #pragma unroll
      for (int r = 0; r < 4; ++r) {
        int t = t0 + wy * 64 + fm * 16 + quad * 4 + r;
        float gate = fminf(ga[r] + bg, 7.0f);
        float up   = fminf(fmaxf(ua[r] + bu, -7.0f), 7.0f);
        float glu  = gate / (1.0f + __expf(-1.702f * gate));
        float a    = (up + 1.0f) * glu;
        act[((size_t)e * Ttok + t) * Idim + ig] = (uint16_t)f2bf(a);
      }
    }
  }
}

// ---------------------------------------------------------------------------
// GEMM2: block owns 64 tokens x 64 h-rows; loops e=0..7 (innermost K over I).
// 4 waves 2x2, wave tile 32x32. At each expert boundary:
//   accO += rw[t,e] * (acc + bias[e,h])   (fp32, exact reference semantics)
// Plain stores at end -> no atomics, no out zero-init.
__global__ __launch_bounds__(256) void gemm2_kernel(
    const uint16_t* __restrict__ act, const int* __restrict__ blocks,
    const int* __restrict__ scales, const float* __restrict__ bias,
    const float* __restrict__ rw, float* __restrict__ out) {
  __shared__ uint16_t sA[64 * 64];
  __shared__ uint16_t sB[64 * 64];
  const int tid  = threadIdx.x;
  const int lane = tid & 63, wv = tid >> 6;
  const int wx = wv & 1, wy = wv >> 1;
  const int col = lane & 15, quad = lane >> 4;
  const int t0 = blockIdx.x * 64;
  const int h0 = blockIdx.y * 64;

  const int d = tid >> 2, sub = tid & 3;  // 4 threads per h-row, half-group each
  floatx4 accO[2][2] = {};

  for (int e = 0; e < E8; ++e) {
    floatx4 acc[2][2] = {};
    const size_t brow = ((size_t)e * Hdim + (h0 + d)) * Gg;
    const uint16_t* aB = act + (size_t)e * Ttok * Idim;

    for (int kt = 0; kt < 45; ++kt) {
      __syncthreads();
      {
        const int k0 = kt * 64;
        #pragma unroll
        for (int q = 0; q < 2; ++q) {
          int L = wv * 128 + q * 64 + lane;
          int row = L >> 3;
          int c = (L & 7) ^ (row & 7);
          load_lds16(aB + (size_t)(t0 + row) * Idim + k0 + c * 8,
                     &sA[(size_t)(wv * 128 + q * 64) * 8]);
        }
      }
      {
        const int g = kt * 2 + (sub >> 1);
        const int4* bp = (const int4*)(blocks + (brow + g) * 16 + (sub & 1) * 8);
        int4 w0 = bp[0], w1 = bp[1];
        DqLut L = make_lut(scales[brow + g]);
        const int m = d & 7;
        *(uint4*)&sB[d * 64 + (((2 * sub) ^ m) * 8)]     = dq8(L, w0);
        *(uint4*)&sB[d * 64 + (((2 * sub + 1) ^ m) * 8)] = dq8(L, w1);
      }
      __syncthreads();
      #pragma unroll
      for (int ks = 0; ks < 2; ++ks) {
        bf16x8 af[2], bfr[2];
        #pragma unroll
        for (int fm = 0; fm < 2; ++fm) {
          int row = wy * 32 + fm * 16 + col;
          int c = ((ks << 2) | quad) ^ (row & 7);
          af[fm] = *(const bf16x8*)&sA[row * 64 + c * 8];
        }
        #pragma unroll
        for (int fn = 0; fn < 2; ++fn) {
          int row = wx * 32 + fn * 16 + col;
          int c = ((ks << 2) | quad) ^ (row & 7);
          bfr[fn] = *(const bf16x8*)&sB[row * 64 + c * 8];
        }
        #pragma unroll
        for (int fm = 0; fm < 2; ++fm)
          #pragma unroll
          for (int fn = 0; fn < 2; ++fn)
            acc[fm][fn] = __builtin_amdgcn_mfma_f32_16x16x32_bf16(
                af[fm], bfr[fn], acc[fm][fn], 0, 0, 0);
      }
    }

    {  // fold expert e: accO += rw * (acc + bias)
      float bb[2];
      #pragma unroll
      for (int fn = 0; fn < 2; ++fn)
        bb[fn] = bias[(size_t)e * Hdim + (h0 + wx * 32 + fn * 16 + col)];
      #pragma unroll
      for (int fm = 0; fm < 2; ++fm) {
        #pragma unroll
        for (int r = 0; r < 4; ++r) {
          int t = t0 + wy * 32 + fm * 16 + quad * 4 + r;
          float wgt = rw[t * E8 + e];
          #pragma unroll
          for (int fn = 0; fn < 2; ++fn)
            accO[fm][fn][r] += wgt * (acc[fm][fn][r] + bb[fn]);
        }
      }
    }
  }

  #pragma unroll
  for (int fm = 0; fm < 2; ++fm)
    #pragma unroll
    for (int fn = 0; fn < 2; ++fn) {
      int h = h0 + wx * 32 + fn * 16 + col;
      #pragma unroll
      for (int r = 0; r < 4; ++r) {
        int t = t0 + wy * 32 + fm * 16 + quad * 4 + r;
        out[(size_t)t * Hdim + h] = accO[fm][fn][r];
      }
    }
}

// ---------------------------------------------------------------------------
extern "C" void kernel_launch(void* const* d_in, const int* in_sizes, int n_in,
                              void* d_out, int out_size, void* d_ws, size_t ws_size,
                              hipStream_t stream) {
  (void)in_sizes; (void)n_in; (void)ws_size; (void)out_size;
  const float* x        = (const float*)d_in[0];
  const float* rw       = (const float*)d_in[1];
  const int*   gub_b    = (const int*)d_in[2];
  const int*   gub_s    = (const int*)d_in[3];
  const float* gub_bias = (const float*)d_in[4];
  const int*   dwn_b    = (const int*)d_in[5];
  const int*   dwn_s    = (const int*)d_in[6];
  const float* dwn_bias = (const float*)d_in[7];
  float* out = (float*)d_out;

  // ws layout: x_bf16 [T,H] (5.9 MB) | act_bf16 [E,T,I] (47.2 MB)
  uint16_t* xb  = (uint16_t*)d_ws;
  uint16_t* act = xb + (size_t)Ttok * Hdim;

  cvt_x_kernel<<<dim3((Ttok * Hdim / 4 + 255) / 256), 256, 0, stream>>>(x, xb, Ttok * Hdim);
  // grid: t-tile fastest so the 8 blocks sharing a weight column are adjacent
  gemm1_kernel<<<dim3(8, 45, 8), 256, 0, stream>>>(xb, gub_b, gub_s, gub_bias, act);
  gemm2_kernel<<<dim3(16, 45), 256, 0, stream>>>(act, dwn_b, dwn_s, dwn_bias, rw, out);
}

// Round 3
// 1245.271 us; speedup vs baseline: 1.0122x; 1.0099x over previous
//
#include <hip/hip_runtime.h>
#include <cstdint>

// ---------------------------------------------------------------------------
// MXFP4 GPT-OSS MoE experts: dense all-expert GLU MLP.
// Round 3: pre-dequantize BOTH weight tensors to bf16 in ws (bf16 weights are
// the same byte-size as the packed-int32 blocks), then run both GEMMs as pure
// m97-style bf16 MFMA kernels with global_load_lds DMA staging for A and B.
// Falls back to the Round-2 fused-dequant path if ws is too small.
// ---------------------------------------------------------------------------

typedef float  floatx4 __attribute__((ext_vector_type(4)));
typedef __bf16 bf16x8  __attribute__((ext_vector_type(8)));

#define E8   8
#define Hdim 2880
#define Idim 2880
#define Ttok 1024
#define R1   5760   // 2*I rows of gate_up weights
#define Gg   90     // groups per row (K/32)

__device__ __forceinline__ void load_lds16(const void* gptr, void* lptr) {
  __builtin_amdgcn_global_load_lds(
      (const __attribute__((address_space(1))) uint32_t*)gptr,
      (__attribute__((address_space(3))) uint32_t*)lptr, 16, 0, 0);
}

__device__ __forceinline__ uint32_t f2bf(float f) {  // RTN-even fp32->bf16
  uint32_t u = __float_as_uint(f);
  return (u + 0x7FFFu + ((u >> 16) & 1u)) >> 16;
}

__device__ __forceinline__ uint32_t perm(uint32_t hi, uint32_t lo, uint32_t sel) {
  return __builtin_amdgcn_perm(hi, lo, sel);
}

// Per-scale-group LUT: bf16 bit patterns of FP4 magnitudes 0..7 scaled by
// 2^(s-127), split into low/high bytes for v_perm lookup. Entry 0 stays 0.
struct DqLut { uint32_t Ll, Lh, Hl, Hh; };

__device__ __forceinline__ DqLut make_lut(int s) {
  uint32_t A  = ((uint32_t)(s - 127) << 7) & 0xFFFFu;
  uint32_t e1 = (0x3F00u + A) & 0xFFFFu, e2 = (0x3F80u + A) & 0xFFFFu;
  uint32_t e3 = (0x3FC0u + A) & 0xFFFFu, e4 = (0x4000u + A) & 0xFFFFu;
  uint32_t e5 = (0x4040u + A) & 0xFFFFu, e6 = (0x4080u + A) & 0xFFFFu;
  uint32_t e7 = (0x40C0u + A) & 0xFFFFu;
  uint32_t B01 = e1 << 16, B23 = e2 | (e3 << 16);
  uint32_t B45 = e4 | (e5 << 16), B67 = e6 | (e7 << 16);
  DqLut L;
  L.Ll = perm(B23, B01, 0x06040200u);
  L.Hl = perm(B23, B01, 0x07050301u);
  L.Lh = perm(B67, B45, 0x06040200u);
  L.Hh = perm(B67, B45, 0x07050301u);
  return L;
}

// 4 source dwords (1 packed byte each) -> 8 bf16 (4 dwords), interleaved order.
__device__ __forceinline__ uint4 dq8(const DqLut& L, int4 wr) {
  uint32_t p = perm((uint32_t)wr.y, (uint32_t)wr.x, 0x04000400u);
  uint32_t q = perm((uint32_t)wr.w, (uint32_t)wr.z, 0x04000400u);
  uint32_t w = perm(q, p, 0x05040100u);
  uint32_t ilo = w & 0x07070707u;
  uint32_t ihi = (w >> 4) & 0x07070707u;
  uint32_t Llo = perm(L.Lh, L.Ll, ilo);
  uint32_t Hlo = perm(L.Hh, L.Hl, ilo) | ((w << 4) & 0x80808080u);
  uint32_t Lhi = perm(L.Lh, L.Ll, ihi);
  uint32_t Hhi = perm(L.Hh, L.Hl, ihi) | (w & 0x80808080u);
  uint32_t t0 = perm(Hlo, Llo, 0x05010400u);
  uint32_t t1 = perm(Hlo, Llo, 0x07030602u);
  uint32_t t2 = perm(Hhi, Lhi, 0x05010400u);
  uint32_t t3 = perm(Hhi, Lhi, 0x07030602u);
  uint4 o;
  o.x = perm(t2, t0, 0x05040100u);
  o.y = perm(t2, t0, 0x07060302u);
  o.z = perm(t3, t1, 0x05040100u);
  o.w = perm(t3, t1, 0x07060302u);
  return o;
}

// ---------------------------------------------------------------------------
__global__ void cvt_x_kernel(const float* __restrict__ x, uint16_t* __restrict__ xb, int n) {
  int i = (blockIdx.x * 256 + threadIdx.x) * 4;
  if (i >= n) return;
  float4 v = *(const float4*)(x + i);
  ushort4 o = make_ushort4((uint16_t)f2bf(v.x), (uint16_t)f2bf(v.y),
                           (uint16_t)f2bf(v.z), (uint16_t)f2bf(v.w));
  *(ushort4*)(xb + i) = o;
}

// Pre-dequant: one thread per scale group (16 int32 = 32 weights -> 64 B bf16).
__global__ void dq_w_kernel(const int* __restrict__ blocks, const int* __restrict__ scales,
                            uint16_t* __restrict__ wd) {
  size_t g = (size_t)blockIdx.x * 256 + threadIdx.x;
  const int4* bp = (const int4*)(blocks + g * 16);
  int4 w0 = bp[0], w1 = bp[1], w2 = bp[2], w3 = bp[3];
  DqLut L = make_lut(scales[g]);
  uint4* op = (uint4*)(wd + g * 32);
  op[0] = dq8(L, w0); op[1] = dq8(L, w1); op[2] = dq8(L, w2); op[3] = dq8(L, w3);
}

// ---------------------------------------------------------------------------
// GEMM1 (pre-dequant): BM=128 tokens x BN=128 f-rows x BK=64, 4 waves 2x2,
// wave tile 64x64. Both tiles DMA-staged; gate/up deinterleave + XOR chunk
// swizzle folded into per-lane GLOBAL addresses (LDS dest stays contiguous).
__global__ __launch_bounds__(256) void gemm1_pd_kernel(
    const uint16_t* __restrict__ xb, const uint16_t* __restrict__ w1d,
    const float* __restrict__ bias, uint16_t* __restrict__ act) {
  __shared__ uint16_t sA[128 * 64];
  __shared__ uint16_t sB[128 * 64];
  const int tid  = threadIdx.x;
  const int lane = tid & 63, wv = tid >> 6;
  const int wx = wv & 1, wy = wv >> 1;
  const int col = lane & 15, quad = lane >> 4;
  const int e  = blockIdx.z;
  const int t0 = blockIdx.x * 128;
  const int i0 = blockIdx.y * 64;

  floatx4 acc[4][4] = {};

  // Per-lane loop-invariant source pointers for the 4 DMA slots of each tile.
  const uint16_t* aSrc[4];
  const uint16_t* bSrc[4];
  uint16_t* aDst[4];
  uint16_t* bDst[4];
  #pragma unroll
  for (int q = 0; q < 4; ++q) {
    int L = wv * 256 + q * 64 + lane;
    int row = L >> 3;
    int c = (L & 7) ^ (row & 7);
    aSrc[q] = xb + (size_t)(t0 + row) * Hdim + c * 8;
    aDst[q] = &sA[(size_t)(wv * 256 + q * 64) * 8];
    // LDS row rho -> original W1 row (gate/up deinterleave):
    int orig = 2 * (((row >> 6) << 5) + (row & 31)) + ((row >> 5) & 1);
    bSrc[q] = w1d + ((size_t)e * R1 + 2 * i0 + orig) * Hdim + c * 8;
    bDst[q] = &sB[(size_t)(wv * 256 + q * 64) * 8];
  }

  for (int kt = 0; kt < 45; ++kt) {
    __syncthreads();
    const int k0 = kt * 64;
    #pragma unroll
    for (int q = 0; q < 4; ++q) load_lds16(aSrc[q] + k0, aDst[q]);
    #pragma unroll
    for (int q = 0; q < 4; ++q) load_lds16(bSrc[q] + k0, bDst[q]);
    __syncthreads();
    #pragma unroll
    for (int ks = 0; ks < 2; ++ks) {
      bf16x8 af[4], bfr[4];
      #pragma unroll
      for (int fm = 0; fm < 4; ++fm) {
        int row = wy * 64 + fm * 16 + col;
        int c = ((ks << 2) | quad) ^ (row & 7);
        af[fm] = *(const bf16x8*)&sA[row * 64 + c * 8];
      }
      #pragma unroll
      for (int fn = 0; fn < 4; ++fn) {
        int row = wx * 64 + fn * 16 + col;
        int c = ((ks << 2) | quad) ^ (row & 7);
        bfr[fn] = *(const bf16x8*)&sB[row * 64 + c * 8];
      }
      #pragma unroll
      for (int fm = 0; fm < 4; ++fm)
        #pragma unroll
        for (int fn = 0; fn < 4; ++fn)
          acc[fm][fn] = __builtin_amdgcn_mfma_f32_16x16x32_bf16(
              af[fm], bfr[fn], acc[fm][fn], 0, 0, 0);
    }
  }

  #pragma unroll
  for (int fm = 0; fm < 4; ++fm) {
    #pragma unroll
    for (int p = 0; p < 2; ++p) {
      floatx4 ga = acc[fm][p], ua = acc[fm][p + 2];
      int ig = i0 + wx * 32 + p * 16 + col;
      float bg = bias[(size_t)e * R1 + 2 * ig];
      float bu = bias[(size_t)e * R1 + 2 * ig + 1];
      #pragma unroll
      for (int r = 0; r < 4; ++r) {
        int t = t0 + wy * 64 + fm * 16 + quad * 4 + r;
        float gate = fminf(ga[r] + bg, 7.0f);
        float up   = fminf(fmaxf(ua[r] + bu, -7.0f), 7.0f);
        float glu  = gate / (1.0f + __expf(-1.702f * gate));
        float a    = (up + 1.0f) * glu;
        act[((size_t)e * Ttok + t) * Idim + ig] = (uint16_t)f2bf(a);
      }
    }
  }
}

// ---------------------------------------------------------------------------
// GEMM2 (pre-dequant): block owns 64 tokens x 64 h-rows; expert loop inside,
// fp32 register fold of rw*(acc+bias), plain stores, no atomics.
__global__ __launch_bounds__(256) void gemm2_pd_kernel(
    const uint16_t* __restrict__ act, const uint16_t* __restrict__ w2d,
    const float* __restrict__ bias, const float* __restrict__ rw,
    float* __restrict__ out) {
  __shared__ uint16_t sA[64 * 64];
  __shared__ uint16_t sB[64 * 64];
  const int tid  = threadIdx.x;
  const int lane = tid & 63, wv = tid >> 6;
  const int wx = wv & 1, wy = wv >> 1;
  const int col = lane & 15, quad = lane >> 4;
  const int h0 = blockIdx.x * 64;   // h fastest: 45 consecutive blocks share A
  const int t0 = blockIdx.y * 64;

  floatx4 accO[2][2] = {};

  int rowQ[2], cQ[2];
  #pragma unroll
  for (int q = 0; q < 2; ++q) {
    int L = wv * 128 + q * 64 + lane;
    rowQ[q] = L >> 3;
    cQ[q] = (L & 7) ^ (rowQ[q] & 7);
  }

  for (int e = 0; e < E8; ++e) {
    floatx4 acc[2][2] = {};
    const uint16_t* aB = act + ((size_t)e * Ttok + t0) * Idim;
    const uint16_t* bB = w2d + ((size_t)e * Hdim + h0) * Idim;

    for (int kt = 0; kt < 45; ++kt) {
      __syncthreads();
      const int k0 = kt * 64;
      #pragma unroll
      for (int q = 0; q < 2; ++q)
        load_lds16(aB + (size_t)rowQ[q] * Idim + k0 + cQ[q] * 8,
                   &sA[(size_t)(wv * 128 + q * 64) * 8]);
      #pragma unroll
      for (int q = 0; q < 2; ++q)
        load_lds16(bB + (size_t)rowQ[q] * Idim + k0 + cQ[q] * 8,
                   &sB[(size_t)(wv * 128 + q * 64) * 8]);
      __syncthreads();
      #pragma unroll
      for (int ks = 0; ks < 2; ++ks) {
        bf16x8 af[2], bfr[2];
        #pragma unroll
        for (int fm = 0; fm < 2; ++fm) {
          int row = wy * 32 + fm * 16 + col;
          int c = ((ks << 2) | quad) ^ (row & 7);
          af[fm] = *(const bf16x8*)&sA[row * 64 + c * 8];
        }
        #pragma unroll
        for (int fn = 0; fn < 2; ++fn) {
          int row = wx * 32 + fn * 16 + col;
          int c = ((ks << 2) | quad) ^ (row & 7);
          bfr[fn] = *(const bf16x8*)&sB[row * 64 + c * 8];
        }
        #pragma unroll
        for (int fm = 0; fm < 2; ++fm)
          #pragma unroll
          for (int fn = 0; fn < 2; ++fn)
            acc[fm][fn] = __builtin_amdgcn_mfma_f32_16x16x32_bf16(
                af[fm], bfr[fn], acc[fm][fn], 0, 0, 0);
      }
    }

    {
      float bb[2];
      #pragma unroll
      for (int fn = 0; fn < 2; ++fn)
        bb[fn] = bias[(size_t)e * Hdim + (h0 + wx * 32 + fn * 16 + col)];
      #pragma unroll
      for (int fm = 0; fm < 2; ++fm) {
        #pragma unroll
        for (int r = 0; r < 4; ++r) {
          int t = t0 + wy * 32 + fm * 16 + quad * 4 + r;
          float wgt = rw[t * E8 + e];
          #pragma unroll
          for (int fn = 0; fn < 2; ++fn)
            accO[fm][fn][r] += wgt * (acc[fm][fn][r] + bb[fn]);
        }
      }
    }
  }

  #pragma unroll
  for (int fm = 0; fm < 2; ++fm)
    #pragma unroll
    for (int fn = 0; fn < 2; ++fn) {
      int h = h0 + wx * 32 + fn * 16 + col;
      #pragma unroll
      for (int r = 0; r < 4; ++r) {
        int t = t0 + wy * 32 + fm * 16 + quad * 4 + r;
        out[(size_t)t * Hdim + h] = accO[fm][fn][r];
      }
    }
}

// ===========================================================================
// Fallback (Round-2 fused-dequant) kernels — used only if ws is too small.
// ===========================================================================
__global__ __launch_bounds__(256) void gemm1_kernel(
    const uint16_t* __restrict__ xb, const int* __restrict__ blocks,
    const int* __restrict__ scales, const float* __restrict__ bias,
    uint16_t* __restrict__ act) {
  __shared__ uint16_t sA[128 * 64];
  __shared__ uint16_t sB[128 * 64];
  const int tid  = threadIdx.x;
  const int lane = tid & 63, wv = tid >> 6;
  const int wx = wv & 1, wy = wv >> 1;
  const int col = lane & 15, quad = lane >> 4;
  const int e  = blockIdx.z;
  const int t0 = blockIdx.x * 128;
  const int i0 = blockIdx.y * 64;

  floatx4 acc[4][4] = {};

  const int d  = tid >> 1, kh = tid & 1;
  const int rho = ((d >> 6) << 6) | ((d & 1) << 5) | ((d >> 1) & 31);
  const size_t brow = ((size_t)e * R1 + (2 * i0 + d)) * Gg;

  for (int kt = 0; kt < 45; ++kt) {
    __syncthreads();
    {
      const int k0 = kt * 64;
      #pragma unroll
      for (int q = 0; q < 4; ++q) {
        int L = wv * 256 + q * 64 + lane;
        int row = L >> 3;
        int c = (L & 7) ^ (row & 7);
        load_lds16(xb + (size_t)(t0 + row) * Hdim + k0 + c * 8,
                   &sA[(size_t)(wv * 256 + q * 64) * 8]);
      }
    }
    {
      const int g = kt * 2 + kh;
      const int4* bp = (const int4*)(blocks + (brow + g) * 16);
      int4 w0 = bp[0], w1 = bp[1], w2 = bp[2], w3 = bp[3];
      DqLut L = make_lut(scales[brow + g]);
      const int base = rho * 64, m = rho & 7;
      *(uint4*)&sB[base + ((((kh << 2) | 0) ^ m) * 8)] = dq8(L, w0);
      *(uint4*)&sB[base + ((((kh << 2) | 1) ^ m) * 8)] = dq8(L, w1);
      *(uint4*)&sB[base + ((((kh << 2) | 2) ^ m) * 8)] = dq8(L, w2);
      *(uint4*)&sB[base + ((((kh << 2) | 3) ^ m) * 8)] = dq8(L, w3);
    }
    __syncthreads();
    #pragma unroll
    for (int ks = 0; ks < 2; ++ks) {
      bf16x8 af[4], bfr[4];
      #pragma unroll
      for (int fm = 0; fm < 4; ++fm) {
        int row = wy * 64 + fm * 16 + col;
        int c = ((ks << 2) | quad) ^ (row & 7);
        af[fm] = *(const bf16x8*)&sA[row * 64 + c * 8];
      }
      #pragma unroll
      for (int fn = 0; fn < 4; ++fn) {
        int row = wx * 64 + fn * 16 + col;
        int c = ((ks << 2) | quad) ^ (row & 7);
        bfr[fn] = *(const bf16x8*)&sB[row * 64 + c * 8];
      }
      #pragma unroll
      for (int fm = 0; fm < 4; ++fm)
        #pragma unroll
        for (int fn = 0; fn < 4; ++fn)
          acc[fm][fn] = __builtin_amdgcn_mfma_f32_16x16x32_bf16(
              af[fm], bfr[fn], acc[fm][fn], 0, 0, 0);
    }
  }

  #pragma unroll
  for (int fm = 0; fm < 4; ++fm) {
    #pragma unroll
    for (int p = 0; p < 2; ++p) {
      floatx4 ga = acc[fm][p], ua = acc[fm][p + 2];
      int ig = i0 + wx * 32 + p * 16 + col;
      float bg = bias[(size_t)e * R1 + 2 * ig];
      float bu = bias[(size_t)e * R1 + 2 * ig + 1];
      #pragma unroll
      for (int r = 0; r < 4; ++r) {
        int t = t0 + wy * 64 + fm * 16 + quad * 4 + r;
        float gate = fminf(ga[r] + bg, 7.0f);
        float up   = fminf(fmaxf(ua[r] + bu, -7.0f), 7.0f);
        float glu  = gate / (1.0f + __expf(-1.702f * gate));
        float a    = (up + 1.0f) * glu;
        act[((size_t)e * Ttok + t) * Idim + ig] = (uint16_t)f2bf(a);
      }
    }
  }
}

__global__ __launch_bounds__(256) void gemm2_kernel(
    const uint16_t* __restrict__ act, const int* __restrict__ blocks,
    const int* __restrict__ scales, const float* __restrict__ bias,
    const float* __restrict__ rw, float* __restrict__ out) {
  __shared__ uint16_t sA[64 * 64];
  __shared__ uint16_t sB[64 * 64];
  const int tid  = threadIdx.x;
  const int lane = tid & 63, wv = tid >> 6;
  const int wx = wv & 1, wy = wv >> 1;
  const int col = lane & 15, quad = lane >> 4;
  const int t0 = blockIdx.x * 64;
  const int h0 = blockIdx.y * 64;

  const int d = tid >> 2, sub = tid & 3;
  floatx4 accO[2][2] = {};

  for (int e = 0; e < E8; ++e) {
    floatx4 acc[2][2] = {};
    const size_t brow = ((size_t)e * Hdim + (h0 + d)) * Gg;
    const uint16_t* aB = act + (size_t)e * Ttok * Idim;

    for (int kt = 0; kt < 45; ++kt) {
      __syncthreads();
      {
        const int k0 = kt * 64;
        #pragma unroll
        for (int q = 0; q < 2; ++q) {
          int L = wv * 128 + q * 64 + lane;
          int row = L >> 3;
          int c = (L & 7) ^ (row & 7);
          load_lds16(aB + (size_t)(t0 + row) * Idim + k0 + c * 8,
                     &sA[(size_t)(wv * 128 + q * 64) * 8]);
        }
      }
      {
        const int g = kt * 2 + (sub >> 1);
        const int4* bp = (const int4*)(blocks + (brow + g) * 16 + (sub & 1) * 8);
        int4 w0 = bp[0], w1 = bp[1];
        DqLut L = make_lut(scales[brow + g]);
        const int m = d & 7;
        *(uint4*)&sB[d * 64 + (((2 * sub) ^ m) * 8)]     = dq8(L, w0);
        *(uint4*)&sB[d * 64 + (((2 * sub + 1) ^ m) * 8)] = dq8(L, w1);
      }
      __syncthreads();
      #pragma unroll
      for (int ks = 0; ks < 2; ++ks) {
        bf16x8 af[2], bfr[2];
        #pragma unroll
        for (int fm = 0; fm < 2; ++fm) {
          int row = wy * 32 + fm * 16 + col;
          int c = ((ks << 2) | quad) ^ (row & 7);
          af[fm] = *(const bf16x8*)&sA[row * 64 + c * 8];
        }
        #pragma unroll
        for (int fn = 0; fn < 2; ++fn) {
          int row = wx * 32 + fn * 16 + col;
          int c = ((ks << 2) | quad) ^ (row & 7);
          bfr[fn] = *(const bf16x8*)&sB[row * 64 + c * 8];
        }
        #pragma unroll
        for (int fm = 0; fm < 2; ++fm)
          #pragma unroll
          for (int fn = 0; fn < 2; ++fn)
            acc[fm][fn] = __builtin_amdgcn_mfma_f32_16x16x32_bf16(
                af[fm], bfr[fn], acc[fm][fn], 0, 0, 0);
      }
    }

    {
      float bb[2];
      #pragma unroll
      for (int fn = 0; fn < 2; ++fn)
        bb[fn] = bias[(size_t)e * Hdim + (h0 + wx * 32 + fn * 16 + col)];
      #pragma unroll
      for (int fm = 0; fm < 2; ++fm) {
        #pragma unroll
        for (int r = 0; r < 4; ++r) {
          int t = t0 + wy * 32 + fm * 16 + quad * 4 + r;
          float wgt = rw[t * E8 + e];
          #pragma unroll
          for (int fn = 0; fn < 2; ++fn)
            accO[fm][fn][r] += wgt * (acc[fm][fn][r] + bb[fn]);
        }
      }
    }
  }

  #pragma unroll
  for (int fm = 0; fm < 2; ++fm)
    #pragma unroll
    for (int fn = 0; fn < 2; ++fn) {
      int h = h0 + wx * 32 + fn * 16 + col;
      #pragma unroll
      for (int r = 0; r < 4; ++r) {
        int t = t0 + wy * 32 + fm * 16 + quad * 4 + r;
        out[(size_t)t * Hdim + h] = accO[fm][fn][r];
      }
    }
}

// ---------------------------------------------------------------------------
extern "C" void kernel_launch(void* const* d_in, const int* in_sizes, int n_in,
                              void* d_out, int out_size, void* d_ws, size_t ws_size,
                              hipStream_t stream) {
  (void)in_sizes; (void)n_in; (void)out_size;
  const float* x        = (const float*)d_in[0];
  const float* rw       = (const float*)d_in[1];
  const int*   gub_b    = (const int*)d_in[2];
  const int*   gub_s    = (const int*)d_in[3];
  const float* gub_bias = (const float*)d_in[4];
  const int*   dwn_b    = (const int*)d_in[5];
  const int*   dwn_s    = (const int*)d_in[6];
  const float* dwn_bias = (const float*)d_in[7];
  float* out = (float*)d_out;

  // ws layout: x_bf16 [T,H] | act [E,T,I] | W1d [E,R1,H] | W2d [E,H,I]  (bf16)
  const size_t nXb  = (size_t)Ttok * Hdim;          //  2.95M
  const size_t nAct = (size_t)E8 * Ttok * Idim;     // 23.6M
  const size_t nW1  = (size_t)E8 * R1 * Hdim;       // 132.7M
  const size_t nW2  = (size_t)E8 * Hdim * Idim;     // 66.4M
  const size_t need = (nXb + nAct + nW1 + nW2) * sizeof(uint16_t);

  uint16_t* xb  = (uint16_t*)d_ws;
  uint16_t* act = xb + nXb;

  cvt_x_kernel<<<dim3((Ttok * Hdim / 4 + 255) / 256), 256, 0, stream>>>(x, xb, Ttok * Hdim);

  if (ws_size >= need) {
    uint16_t* w1d = act + nAct;
    uint16_t* w2d = w1d + nW1;
    dq_w_kernel<<<dim3((int)(E8 * (size_t)R1 * Gg / 256)), 256, 0, stream>>>(gub_b, gub_s, w1d);
    dq_w_kernel<<<dim3((int)(E8 * (size_t)Hdim * Gg / 256)), 256, 0, stream>>>(dwn_b, dwn_s, w2d);
    gemm1_pd_kernel<<<dim3(8, 45, 8), 256, 0, stream>>>(xb, w1d, gub_bias, act);
    gemm2_pd_kernel<<<dim3(45, 16), 256, 0, stream>>>(act, w2d, dwn_bias, rw, out);
  } else {
    gemm1_kernel<<<dim3(8, 45, 8), 256, 0, stream>>>(xb, gub_b, gub_s, gub_bias, act);
    gemm2_kernel<<<dim3(16, 45), 256, 0, stream>>>(act, dwn_b, dwn_s, dwn_bias, rw, out);
  }
}

// Round 4
// 1189.348 us; speedup vs baseline: 1.0598x; 1.0470x over previous
//
#include <hip/hip_runtime.h>
#include <cstdint>

// ---------------------------------------------------------------------------
// MXFP4 GPT-OSS MoE experts: dense all-expert GLU MLP.
// Round 4: rw folded into act at gemm1 epilogue; act stored [t][(e,i)] so
// GEMM2 is ONE plain BT GEMM with K=23040 (W2 pre-dequantized transposed to
// [h][(e,i)]). Rank-8 bias term written by bias_init; gemm2 atomicAdds onto
// it (K-split 2). Both GEMMs are m97-structure bf16 MFMA with DMA staging.
// ---------------------------------------------------------------------------

typedef float  floatx4 __attribute__((ext_vector_type(4)));
typedef __bf16 bf16x8  __attribute__((ext_vector_type(8)));

#define E8   8
#define Hdim 2880
#define Idim 2880
#define Ttok 1024
#define R1   5760   // 2*I rows of gate_up weights
#define Gg   90     // scale groups per row (K/32)
#define K2   (E8 * Idim)   // 23040 flattened (e,i) K for GEMM2

__device__ __forceinline__ void load_lds16(const void* gptr, void* lptr) {
  __builtin_amdgcn_global_load_lds(
      (const __attribute__((address_space(1))) uint32_t*)gptr,
      (__attribute__((address_space(3))) uint32_t*)lptr, 16, 0, 0);
}

__device__ __forceinline__ uint32_t f2bf(float f) {  // RTN-even fp32->bf16
  uint32_t u = __float_as_uint(f);
  return (u + 0x7FFFu + ((u >> 16) & 1u)) >> 16;
}

__device__ __forceinline__ uint32_t perm(uint32_t hi, uint32_t lo, uint32_t sel) {
  return __builtin_amdgcn_perm(hi, lo, sel);
}

// Per-scale-group LUT: bf16 bit patterns of FP4 magnitudes 0..7 scaled by
// 2^(s-127), split into low/high bytes for v_perm lookup. Entry 0 stays 0.
struct DqLut { uint32_t Ll, Lh, Hl, Hh; };

__device__ __forceinline__ DqLut make_lut(int s) {
  uint32_t A  = ((uint32_t)(s - 127) << 7) & 0xFFFFu;
  uint32_t e1 = (0x3F00u + A) & 0xFFFFu, e2 = (0x3F80u + A) & 0xFFFFu;
  uint32_t e3 = (0x3FC0u + A) & 0xFFFFu, e4 = (0x4000u + A) & 0xFFFFu;
  uint32_t e5 = (0x4040u + A) & 0xFFFFu, e6 = (0x4080u + A) & 0xFFFFu;
  uint32_t e7 = (0x40C0u + A) & 0xFFFFu;
  uint32_t B01 = e1 << 16, B23 = e2 | (e3 << 16);
  uint32_t B45 = e4 | (e5 << 16), B67 = e6 | (e7 << 16);
  DqLut L;
  L.Ll = perm(B23, B01, 0x06040200u);
  L.Hl = perm(B23, B01, 0x07050301u);
  L.Lh = perm(B67, B45, 0x06040200u);
  L.Hh = perm(B67, B45, 0x07050301u);
  return L;
}

// 4 source dwords (1 packed byte each) -> 8 bf16 (4 dwords), interleaved order.
__device__ __forceinline__ uint4 dq8(const DqLut& L, int4 wr) {
  uint32_t p = perm((uint32_t)wr.y, (uint32_t)wr.x, 0x04000400u);
  uint32_t q = perm((uint32_t)wr.w, (uint32_t)wr.z, 0x04000400u);
  uint32_t w = perm(q, p, 0x05040100u);
  uint32_t ilo = w & 0x07070707u;
  uint32_t ihi = (w >> 4) & 0x07070707u;
  uint32_t Llo = perm(L.Lh, L.Ll, ilo);
  uint32_t Hlo = perm(L.Hh, L.Hl, ilo) | ((w << 4) & 0x80808080u);
  uint32_t Lhi = perm(L.Lh, L.Ll, ihi);
  uint32_t Hhi = perm(L.Hh, L.Hl, ihi) | (w & 0x80808080u);
  uint32_t t0 = perm(Hlo, Llo, 0x05010400u);
  uint32_t t1 = perm(Hlo, Llo, 0x07030602u);
  uint32_t t2 = perm(Hhi, Lhi, 0x05010400u);
  uint32_t t3 = perm(Hhi, Lhi, 0x07030602u);
  uint4 o;
  o.x = perm(t2, t0, 0x05040100u);
  o.y = perm(t2, t0, 0x07060302u);
  o.z = perm(t3, t1, 0x05040100u);
  o.w = perm(t3, t1, 0x07060302u);
  return o;
}

// ---------------------------------------------------------------------------
__global__ void cvt_x_kernel(const float* __restrict__ x, uint16_t* __restrict__ xb, int n) {
  int i = (blockIdx.x * 256 + threadIdx.x) * 4;
  if (i >= n) return;
  float4 v = *(const float4*)(x + i);
  ushort4 o = make_ushort4((uint16_t)f2bf(v.x), (uint16_t)f2bf(v.y),
                           (uint16_t)f2bf(v.z), (uint16_t)f2bf(v.w));
  *(ushort4*)(xb + i) = o;
}

// W1 pre-dequant: one thread per scale group, layout preserved [e][r][h].
__global__ void dq_w_kernel(const int* __restrict__ blocks, const int* __restrict__ scales,
                            uint16_t* __restrict__ wd) {
  size_t g = (size_t)blockIdx.x * 256 + threadIdx.x;
  const int4* bp = (const int4*)(blocks + g * 16);
  int4 w0 = bp[0], w1 = bp[1], w2 = bp[2], w3 = bp[3];
  DqLut L = make_lut(scales[g]);
  uint4* op = (uint4*)(wd + g * 32);
  op[0] = dq8(L, w0); op[1] = dq8(L, w1); op[2] = dq8(L, w2); op[3] = dq8(L, w3);
}

// W2 pre-dequant TRANSPOSED: [e][h][i] blocks -> [h][e*Idim + i] bf16.
__global__ void dq_w2t_kernel(const int* __restrict__ blocks, const int* __restrict__ scales,
                              uint16_t* __restrict__ wt) {
  size_t g = (size_t)blockIdx.x * 256 + threadIdx.x;
  int e  = (int)(g / ((size_t)Hdim * Gg));
  int rm = (int)(g % ((size_t)Hdim * Gg));
  int h  = rm / Gg;
  int ig = rm % Gg;
  const int4* bp = (const int4*)(blocks + g * 16);
  int4 w0 = bp[0], w1 = bp[1], w2 = bp[2], w3 = bp[3];
  DqLut L = make_lut(scales[g]);
  uint4* op = (uint4*)(wt + ((size_t)h * E8 + e) * Idim + (size_t)ig * 32);
  op[0] = dq8(L, w0); op[1] = dq8(L, w1); op[2] = dq8(L, w2); op[3] = dq8(L, w3);
}

// out[t,h] = sum_e rw[t,e] * down_bias[e,h]   (gemm2 atomicAdds on top)
__global__ void bias_init_kernel(const float* __restrict__ rw, const float* __restrict__ bias,
                                 float* __restrict__ out) {
  int t  = blockIdx.y;
  int h4 = (blockIdx.x * 256 + threadIdx.x) * 4;
  if (h4 >= Hdim) return;
  float4 s = make_float4(0.f, 0.f, 0.f, 0.f);
  #pragma unroll
  for (int e = 0; e < E8; ++e) {
    float w = rw[t * E8 + e];
    float4 b = *(const float4*)(bias + (size_t)e * Hdim + h4);
    s.x += w * b.x; s.y += w * b.y; s.z += w * b.z; s.w += w * b.w;
  }
  *(float4*)(out + (size_t)t * Hdim + h4) = s;
}

// ---------------------------------------------------------------------------
// GEMM1: BM=128 tokens x BN=128 f-rows x BK=64, 4 waves 2x2, wave tile 64x64.
// Epilogue: GLU + bias, PRE-MULTIPLY by rw[t,e], store bf16 to act[t][(e,i)].
__global__ __launch_bounds__(256) void gemm1_pd_kernel(
    const uint16_t* __restrict__ xb, const uint16_t* __restrict__ w1d,
    const float* __restrict__ bias, const float* __restrict__ rw,
    uint16_t* __restrict__ act) {
  __shared__ uint16_t sA[128 * 64];
  __shared__ uint16_t sB[128 * 64];
  const int tid  = threadIdx.x;
  const int lane = tid & 63, wv = tid >> 6;
  const int wx = wv & 1, wy = wv >> 1;
  const int col = lane & 15, quad = lane >> 4;
  const int e  = blockIdx.z;
  const int t0 = blockIdx.x * 128;
  const int i0 = blockIdx.y * 64;

  floatx4 acc[4][4] = {};

  const uint16_t* aSrc[4];
  const uint16_t* bSrc[4];
  uint16_t* aDst[4];
  uint16_t* bDst[4];
  #pragma unroll
  for (int q = 0; q < 4; ++q) {
    int L = wv * 256 + q * 64 + lane;
    int row = L >> 3;
    int c = (L & 7) ^ (row & 7);
    aSrc[q] = xb + (size_t)(t0 + row) * Hdim + c * 8;
    aDst[q] = &sA[(size_t)(wv * 256 + q * 64) * 8];
    int orig = 2 * (((row >> 6) << 5) + (row & 31)) + ((row >> 5) & 1);  // deinterleave
    bSrc[q] = w1d + ((size_t)e * R1 + 2 * i0 + orig) * Hdim + c * 8;
    bDst[q] = &sB[(size_t)(wv * 256 + q * 64) * 8];
  }

  for (int kt = 0; kt < 45; ++kt) {
    __syncthreads();
    const int k0 = kt * 64;
    #pragma unroll
    for (int q = 0; q < 4; ++q) load_lds16(aSrc[q] + k0, aDst[q]);
    #pragma unroll
    for (int q = 0; q < 4; ++q) load_lds16(bSrc[q] + k0, bDst[q]);
    __syncthreads();
    #pragma unroll
    for (int ks = 0; ks < 2; ++ks) {
      bf16x8 af[4], bfr[4];
      #pragma unroll
      for (int fm = 0; fm < 4; ++fm) {
        int row = wy * 64 + fm * 16 + col;
        int c = ((ks << 2) | quad) ^ (row & 7);
        af[fm] = *(const bf16x8*)&sA[row * 64 + c * 8];
      }
      #pragma unroll
      for (int fn = 0; fn < 4; ++fn) {
        int row = wx * 64 + fn * 16 + col;
        int c = ((ks << 2) | quad) ^ (row & 7);
        bfr[fn] = *(const bf16x8*)&sB[row * 64 + c * 8];
      }
      #pragma unroll
      for (int fm = 0; fm < 4; ++fm)
        #pragma unroll
        for (int fn = 0; fn < 4; ++fn)
          acc[fm][fn] = __builtin_amdgcn_mfma_f32_16x16x32_bf16(
              af[fm], bfr[fn], acc[fm][fn], 0, 0, 0);
    }
  }

  #pragma unroll
  for (int fm = 0; fm < 4; ++fm) {
    #pragma unroll
    for (int p = 0; p < 2; ++p) {
      floatx4 ga = acc[fm][p], ua = acc[fm][p + 2];
      int ig = i0 + wx * 32 + p * 16 + col;
      float bg = bias[(size_t)e * R1 + 2 * ig];
      float bu = bias[(size_t)e * R1 + 2 * ig + 1];
      #pragma unroll
      for (int r = 0; r < 4; ++r) {
        int t = t0 + wy * 64 + fm * 16 + quad * 4 + r;
        float gate = fminf(ga[r] + bg, 7.0f);
        float up   = fminf(fmaxf(ua[r] + bu, -7.0f), 7.0f);
        float glu  = gate / (1.0f + __expf(-1.702f * gate));
        float a    = rw[t * E8 + e] * (up + 1.0f) * glu;
        act[((size_t)t * E8 + e) * Idim + ig] = (uint16_t)f2bf(a);
      }
    }
  }
}

// ---------------------------------------------------------------------------
// GEMM2: plain BT GEMM, M=1024 tokens x N=2880 h x K=23040. BM=128, BN=96,
// BK=64, K-split 2 (grid.z). 4 waves 2x2, wave tile 64x48. atomicAdd epilogue
// onto bias_init'd out.
__global__ __launch_bounds__(256) void gemm2_ks_kernel(
    const uint16_t* __restrict__ actT, const uint16_t* __restrict__ w2t,
    float* __restrict__ out) {
  __shared__ uint16_t sA[128 * 64];
  __shared__ uint16_t sB[96 * 64];
  const int tid  = threadIdx.x;
  const int lane = tid & 63, wv = tid >> 6;
  const int wx = wv & 1, wy = wv >> 1;
  const int col = lane & 15, quad = lane >> 4;
  const int t0 = blockIdx.x * 128;
  const int h0 = blockIdx.y * 96;
  const int kbase = blockIdx.z * (K2 / 2);   // 11520 per split

  floatx4 acc[4][3] = {};

  const uint16_t* aSrc[4];
  uint16_t* aDst[4];
  #pragma unroll
  for (int q = 0; q < 4; ++q) {
    int L = wv * 256 + q * 64 + lane;
    int row = L >> 3;
    int c = (L & 7) ^ (row & 7);
    aSrc[q] = actT + (size_t)(t0 + row) * K2 + kbase + c * 8;
    aDst[q] = &sA[(size_t)(wv * 256 + q * 64) * 8];
  }
  const uint16_t* bSrc[3];
  uint16_t* bDst[3];
  #pragma unroll
  for (int q = 0; q < 3; ++q) {
    int L = wv * 192 + q * 64 + lane;
    int row = L >> 3;
    int c = (L & 7) ^ (row & 7);
    bSrc[q] = w2t + (size_t)(h0 + row) * K2 + kbase + c * 8;
    bDst[q] = &sB[(size_t)(wv * 192 + q * 64) * 8];
  }

  for (int kt = 0; kt < 180; ++kt) {
    __syncthreads();
    const int k0 = kt * 64;
    #pragma unroll
    for (int q = 0; q < 4; ++q) load_lds16(aSrc[q] + k0, aDst[q]);
    #pragma unroll
    for (int q = 0; q < 3; ++q) load_lds16(bSrc[q] + k0, bDst[q]);
    __syncthreads();
    #pragma unroll
    for (int ks = 0; ks < 2; ++ks) {
      bf16x8 af[4], bfr[3];
      #pragma unroll
      for (int fm = 0; fm < 4; ++fm) {
        int row = wy * 64 + fm * 16 + col;
        int c = ((ks << 2) | quad) ^ (row & 7);
        af[fm] = *(const bf16x8*)&sA[row * 64 + c * 8];
      }
      #pragma unroll
      for (int fn = 0; fn < 3; ++fn) {
        int row = wx * 48 + fn * 16 + col;
        int c = ((ks << 2) | quad) ^ (row & 7);
        bfr[fn] = *(const bf16x8*)&sB[row * 64 + c * 8];
      }
      #pragma unroll
      for (int fm = 0; fm < 4; ++fm)
        #pragma unroll
        for (int fn = 0; fn < 3; ++fn)
          acc[fm][fn] = __builtin_amdgcn_mfma_f32_16x16x32_bf16(
              af[fm], bfr[fn], acc[fm][fn], 0, 0, 0);
    }
  }

  #pragma unroll
  for (int fm = 0; fm < 4; ++fm)
    #pragma unroll
    for (int fn = 0; fn < 3; ++fn) {
      int h = h0 + wx * 48 + fn * 16 + col;
      #pragma unroll
      for (int r = 0; r < 4; ++r) {
        int t = t0 + wy * 64 + fm * 16 + quad * 4 + r;
        atomicAdd(out + (size_t)t * Hdim + h, acc[fm][fn][r]);
      }
    }
}

// ---------------------------------------------------------------------------
extern "C" void kernel_launch(void* const* d_in, const int* in_sizes, int n_in,
                              void* d_out, int out_size, void* d_ws, size_t ws_size,
                              hipStream_t stream) {
  (void)in_sizes; (void)n_in; (void)out_size; (void)ws_size;
  const float* x        = (const float*)d_in[0];
  const float* rw       = (const float*)d_in[1];
  const int*   gub_b    = (const int*)d_in[2];
  const int*   gub_s    = (const int*)d_in[3];
  const float* gub_bias = (const float*)d_in[4];
  const int*   dwn_b    = (const int*)d_in[5];
  const int*   dwn_s    = (const int*)d_in[6];
  const float* dwn_bias = (const float*)d_in[7];
  float* out = (float*)d_out;

  // ws layout (bf16 elems): xb [T,H] | act [T, E*I] | W1d [E,R1,H] | W2t [H, E*I]
  // total = (2.95M + 23.6M + 132.7M + 66.4M)*2B = 451.2 MB (same as Round 3, proven to fit)
  const size_t nXb  = (size_t)Ttok * Hdim;
  const size_t nAct = (size_t)Ttok * K2;
  const size_t nW1  = (size_t)E8 * R1 * Hdim;

  uint16_t* xb  = (uint16_t*)d_ws;
  uint16_t* act = xb + nXb;
  uint16_t* w1d = act + nAct;
  uint16_t* w2t = w1d + nW1;

  cvt_x_kernel<<<dim3((Ttok * Hdim / 4 + 255) / 256), 256, 0, stream>>>(x, xb, Ttok * Hdim);
  dq_w_kernel<<<dim3((int)((size_t)E8 * R1 * Gg / 256)), 256, 0, stream>>>(gub_b, gub_s, w1d);
  dq_w2t_kernel<<<dim3((int)((size_t)E8 * Hdim * Gg / 256)), 256, 0, stream>>>(dwn_b, dwn_s, w2t);
  bias_init_kernel<<<dim3(3, Ttok), 256, 0, stream>>>(rw, dwn_bias, out);
  gemm1_pd_kernel<<<dim3(8, 45, 8), 256, 0, stream>>>(xb, w1d, gub_bias, rw, act);
  gemm2_ks_kernel<<<dim3(8, 30, 2), 256, 0, stream>>>(act, w2t, out);
}